// Round 1
// baseline (163.456 us; speedup 1.0000x reference)
//
#include <hip/hip_runtime.h>

typedef __bf16 bf16x8 __attribute__((ext_vector_type(8)));
typedef float f32x4 __attribute__((ext_vector_type(4)));
typedef unsigned short u16;
typedef unsigned int u32;

__device__ __forceinline__ float bf2f(u16 v) {
    union { unsigned u; float f; } x; x.u = ((unsigned)v) << 16; return x.f;
}
__device__ __forceinline__ u16 f2bf(float f) {
    union { float f; unsigned u; } x; x.f = f;
    unsigned r = x.u + 0x7fffu + ((x.u >> 16) & 1u);
    return (u16)(r >> 16);
}

// Runtime dtype probe (HW-verified r4): f32 buffer -> low u16 of each word is
// mantissa bits -> bf16-exponent ~uniform (~44% >= 0x90); bf16 buffer -> 0 hits.
__device__ __forceinline__ bool probe_is_f32(const void* xp) {
    const unsigned* p = (const unsigned*)xp;
    int hits = 0;
#pragma unroll
    for (int i = 0; i < 32; i++) {
        const unsigned e = (p[i] >> 7) & 0xffu;
        hits += (e >= 0x90u) ? 1 : 0;
    }
    return hits > 3;
}

__device__ __forceinline__ float ld1(const void* p, size_t i, bool isf32) {
    return isf32 ? ((const float*)p)[i] : bf2f(((const u16*)p)[i]);
}

// Async global->LDS DMA, 16B/lane; LDS dest = wave-uniform base + lane*16.
__device__ __forceinline__ void gl2lds16(const void* g, void* l) {
    __builtin_amdgcn_global_load_lds(
        (const __attribute__((address_space(1))) u32*)g,
        (__attribute__((address_space(3))) u32*)l, 16, 0, 0);
}

// One-shot input normalization: everything -> bf16, rpb -> f32 * log2(e).
__global__ __launch_bounds__(256)
void convert_inputs(const void* __restrict__ x, const void* __restrict__ qw,
                    const void* __restrict__ qb, const void* __restrict__ pw,
                    const void* __restrict__ pb, const void* __restrict__ rp,
                    u16* __restrict__ xbf, u16* __restrict__ qwbf,
                    u16* __restrict__ qbbf, u16* __restrict__ pwbf,
                    u16* __restrict__ pbbf, float* __restrict__ rpl2e)
{
    const bool isf32 = probe_is_f32(x);
    const int gid = blockIdx.x * 256 + threadIdx.x;
    const int gsz = gridDim.x * 256;

    struct Seg { const void* s; u16* d; int n; };
    const Seg segs[5] = {{x, xbf, 4194304}, {qw, qwbf, 786432}, {pw, pwbf, 262144},
                         {qb, qbbf, 1536}, {pb, pbbf, 512}};
    for (int t = 0; t < 5; t++) {
        const int n4 = segs[t].n >> 2;
        if (isf32) {
            const f32x4* s = (const f32x4*)segs[t].s;
            for (int i = gid; i < n4; i += gsz) {
                f32x4 v = s[i];
                ushort4 o;
                o.x = f2bf(v[0]); o.y = f2bf(v[1]); o.z = f2bf(v[2]); o.w = f2bf(v[3]);
                *(ushort4*)(segs[t].d + i * 4) = o;
            }
        } else {
            const ushort4* s = (const ushort4*)segs[t].s;
            for (int i = gid; i < n4; i += gsz) *(ushort4*)(segs[t].d + i * 4) = s[i];
        }
    }
    for (int i = gid; i < 63504; i += gsz)
        rpl2e[i] = ld1(rp, i, isf32) * 1.4426950408889634f;
}

// GEMM D = A(MxK) @ W(NoutxK)^T + bias, pure bf16, fp32 accum. BMx128 tile.
// K-loop unrolled x2 with TWO independent BK=32 LDS buffers per operand:
// one barrier-pair per 64 of K (halves the m97-structure barrier drains)
// while keeping the proven conflict-free stride-32 per-buffer layout.
// MODE 0: bias[col]; dual-dtype row-major store to d_out (probe decides).
// MODE 1 (TRANSPOSED QKV): A = qkv_w (rows = channels), W-arg = x (rows =
//   tokens). D[ch][tok]. bias[row]. which = m0>>9 block-uniform.
//   q,k -> [b][h][t][c] packed ushort4; v -> [b][h][c][t] scalar.
template<int MODE, int BM>
__global__ __launch_bounds__(256, MODE == 1 ? 3 : 4)
void gemm_bt(const u16* __restrict__ A, const u16* __restrict__ W,
             const u16* __restrict__ bias, void* __restrict__ out,
             u16* __restrict__ q_out, u16* __restrict__ k_out, u16* __restrict__ v_out,
             const void* __restrict__ probe, int Nout, int K)
{
    __shared__ __align__(16) u16 As[2][BM * 32];
    __shared__ __align__(16) u16 Ws[2][128 * 32];
    constexpr int RW = BM / 32;            // A-frags per wave

    const int tid  = threadIdx.x;
    const int lane = tid & 63;
    const int wave = tid >> 6;
    const int quad = lane >> 4;
    const int l16  = lane & 15;
    const int m0 = blockIdx.y * BM;
    const int n0 = blockIdx.x * 128;
    const int wm = (wave >> 1) * (BM / 2);
    const int wn = (wave & 1) * 64;

    f32x4 acc[RW][4] = {};

    for (int k0 = 0; k0 < K; k0 += 64) {
        __syncthreads();
        for (int u = 0; u < 2; u++) {
            {
                const u16* g = A + (size_t)(m0 + wave * 16 + (lane >> 2)) * K
                                 + k0 + u * 32 + (lane & 3) * 8;
                u16* l = As[u] + wave * 16 * 32;
                for (int p = 0; p < BM / 64; p++) gl2lds16(g + (size_t)p * 64 * K, l + p * 64 * 32);
            }
            {
                const u16* g = W + (size_t)(n0 + wave * 16 + (lane >> 2)) * K
                                 + k0 + u * 32 + (lane & 3) * 8;
                u16* l = Ws[u] + wave * 16 * 32;
                for (int p = 0; p < 2; p++) gl2lds16(g + (size_t)p * 64 * K, l + p * 64 * 32);
            }
        }
        __syncthreads();

        for (int u = 0; u < 2; u++) {
            bf16x8 af[RW], wf[4];
            for (int i = 0; i < RW; i++)
                af[i] = *(const bf16x8*)(As[u] + (wm + i * 16 + l16) * 32 + quad * 8);
            for (int j = 0; j < 4; j++)
                wf[j] = *(const bf16x8*)(Ws[u] + (wn + j * 16 + l16) * 32 + quad * 8);
            for (int i = 0; i < RW; i++)
                for (int j = 0; j < 4; j++)
                    acc[i][j] = __builtin_amdgcn_mfma_f32_16x16x32_bf16(af[i], wf[j], acc[i][j], 0, 0, 0);
        }
    }

    // D layout per 16x16 tile: row = quad*4 + r, col = l16
    if (MODE == 0) {
        const bool isf32 = probe_is_f32(probe);
        for (int j = 0; j < 4; j++) {
            const int col = n0 + wn + j * 16 + l16;
            const float bv = bf2f(bias[col]);
            for (int i = 0; i < RW; i++) {
                const int rbase = m0 + wm + i * 16 + quad * 4;
                for (int r = 0; r < 4; r++) {
                    const float val = acc[i][j][r] + bv;
                    if (isf32) ((float*)out)[(size_t)(rbase + r) * Nout + col] = val;
                    else       ((u16*)out)[(size_t)(rbase + r) * Nout + col]  = f2bf(val);
                }
            }
        }
    } else {
        const int which = m0 >> 9;       // block-uniform (m0 128-aligned)
        float bv[RW][4];
        for (int i = 0; i < RW; i++) {
            const int row4 = m0 + wm + i * 16 + quad * 4;
            for (int r = 0; r < 4; r++) bv[i][r] = bf2f(bias[row4 + r]);
        }
        for (int j = 0; j < 4; j++) {
            const int tok = n0 + wn + j * 16 + l16;
            const int bi = tok >> 10, t = tok & 1023;
            for (int i = 0; i < RW; i++) {
                const int row4 = m0 + wm + i * 16 + quad * 4;
                const int h = (row4 >> 5) & 15;
                const int c = row4 & 31;
                if (which == 2) {        // v: [b][h][c][t]
                    for (int r = 0; r < 4; r++)
                        v_out[((size_t)(bi * 16 + h) * 32 + c + r) * 1024 + t] =
                            f2bf(acc[i][j][r] + bv[i][r]);
                } else {                 // q,k: [b][h][t][c], 8B packed
                    u16* dst = which ? k_out : q_out;
                    ushort4 pk;
                    pk.x = f2bf(acc[i][j][0] + bv[i][0]);
                    pk.y = f2bf(acc[i][j][1] + bv[i][1]);
                    pk.z = f2bf(acc[i][j][2] + bv[i][2]);
                    pk.w = f2bf(acc[i][j][3] + bv[i][3]);
                    *(ushort4*)(dst + ((size_t)(bi * 16 + h) * 1024 + t) * 32 + c) = pk;
                }
            }
        }
    }
}

// Flash attention, S^T formulation, offset-free softmax, MFMA denominator,
// zero shuffles (validated r8). Q frags direct from global; V frags hoisted.
// XCD-SWIZZLED GRID (r10): grid (16,8,8) x=h,y=qt,z=b -> linear ids of the 8
// qt-blocks of a (b,h) differ by 16 -> same XCD (id%8=h%8) -> K/V (128 KB)
// served from that XCD's L2; 16 (b,h)/XCD = 2 MB < 4 MB L2. All 1024 blocks
// co-resident (4/CU).
//
// r11 (this round): K/V fragments read DIRECTLY FROM GLOBAL (XCD-L2 hits by
// the swizzle above) instead of LDS staging. Theory: attn is LDS-unit bound
// (~250-300 LDS cyc/wave/kt); staging K/V through LDS multiplies bandwidth we
// don't need since L2 already holds the tiles. Deletes Ks/Vt buffers, the
// kreg/vreg prefetch, the staging writes, 8 LDS reads/kt/wave AND the per-kt
// __syncthreads (Ps is wave-private, biasS read-only) -> barrier-free main
// loop, waves latency-hide freely. T5 setprio around MFMA clusters (attn
// +4-7% per m191). Ps stride 72 (>=64 required; conflict-balanced).
__global__ __launch_bounds__(256, 4)
void attn(const u16* __restrict__ q, const u16* __restrict__ k,
          const u16* __restrict__ vt, const float* __restrict__ rpl2e,
          u16* __restrict__ o)
{
    __shared__ __align__(16) u16 Ps[4][16 * 72];
    __shared__ float biasS[35 * 63];

    const int tid  = threadIdx.x;
    const int lane = tid & 63;
    const int wave = tid >> 6;
    const int quad = lane >> 4;
    const int l16  = lane & 15;

    const int h  = blockIdx.x;   // 16 heads (fastest -> fixes XCD class)
    const int qt = blockIdx.y;   // 8 q-tiles of 128
    const int b  = blockIdx.z;
    const int n0 = qt * 128;
    const size_t base = ((size_t)(b * 16 + h)) * 32768;  // q,k [t][c]; vt [c][t]

    // ---- prologue: bias region to LDS, Q frags from global ----
    {
        const int row0 = 28 - 4 * qt;
        for (int idx = tid; idx < 2205; idx += 256)
            biasS[idx] = rpl2e[(size_t)h * 3969 + (size_t)(row0 + idx / 63) * 63 + idx % 63];
    }

    bf16x8 qf[2];
    for (int g = 0; g < 2; g++) {
        union { uint4 u; bf16x8 f; } cv;
        cv.u = *(const uint4*)(q + base + (size_t)(n0 + g * 64 + wave * 16 + l16) * 32 + quad * 8);
        qf[g] = cv.f;
    }
    __syncthreads();   // biasS ready; last barrier in the kernel

    bf16x8 ones;
    for (int i = 0; i < 8; i++) ones[i] = (__bf16)1.0f;

    // o_acc[g][0..1] = O columns ct*16+l16; o_acc[g][2] = denominator l
    f32x4 o_acc[2][3] = {};
    const int bn = (wave & 1) * 16 + l16;   // n & 31 (group-invariant)
    const float SC = 0.25503485724582146f;  // d^-0.5 * log2(e)
    u16* pw = Ps[wave];

    for (int kt = 0; kt < 16; kt++) {
        const int mn = kt * 64;

        // K/V fragments straight from global (XCD-L2 resident, 16B/lane)
        bf16x8 kf[4], vf[2][2];
        for (int j = 0; j < 4; j++) {
            union { uint4 u; bf16x8 f; } cv;
            cv.u = *(const uint4*)(k + base + (size_t)(mn + j * 16 + l16) * 32 + quad * 8);
            kf[j] = cv.f;
        }
        for (int kc = 0; kc < 2; kc++)
            for (int ct = 0; ct < 2; ct++) {
                union { uint4 u; bf16x8 f; } cv;
                cv.u = *(const uint4*)(vt + base + (size_t)(ct * 16 + l16) * 1024
                                       + mn + kc * 32 + quad * 8);
                vf[kc][ct] = cv.f;
            }

        for (int g = 0; g < 2; g++) {
            // S^T tile: D col n=l16, row m_loc = j*16 + quad*4 + r
            f32x4 s4[4];
            const f32x4 zero = {};
            __builtin_amdgcn_s_setprio(1);
            for (int j = 0; j < 4; j++)
                s4[j] = __builtin_amdgcn_mfma_f32_16x16x32_bf16(kf[j], qf[g], zero, 0, 0, 0);
            __builtin_amdgcn_s_setprio(0);

            const int rbase = 2 * kt - (wave >> 1) - 2 * g + 3;
            for (int j = 0; j < 4; j++) {
                const float* brow = biasS + (rbase + (j >> 1)) * 63
                                   + ((j & 1) * 16 + quad * 4) - bn + 31;
                ushort4 pk;
                u16* pks = (u16*)&pk;
                for (int r = 0; r < 4; r++) {
                    const float pv = __builtin_amdgcn_exp2f(s4[j][r] * SC + brow[r]);
                    union { __bf16 b; u16 u; } cv; cv.b = (__bf16)pv;
                    pks[r] = cv.u;
                }
                // P[n=l16][m = j*16 + quad*4 + r] -> one 8B store
                *(ushort4*)(pw + l16 * 72 + j * 16 + quad * 4) = pk;
            }

            // O += P·V and l += P·1 (in-wave DS ordering covers write->read)
            __builtin_amdgcn_s_setprio(1);
            for (int kc = 0; kc < 2; kc++) {
                const bf16x8 pa = *(const bf16x8*)(pw + l16 * 72 + kc * 32 + quad * 8);
                for (int ct = 0; ct < 2; ct++)
                    o_acc[g][ct] = __builtin_amdgcn_mfma_f32_16x16x32_bf16(pa, vf[kc][ct], o_acc[g][ct], 0, 0, 0);
                o_acc[g][2] = __builtin_amdgcn_mfma_f32_16x16x32_bf16(pa, ones, o_acc[g][2], 0, 0, 0);
            }
            __builtin_amdgcn_s_setprio(0);
        }
    }

    for (int g = 0; g < 2; g++)
        for (int r = 0; r < 4; r++) {
            const float inv = __builtin_amdgcn_rcpf(o_acc[g][2][r]);
            const int n = n0 + g * 64 + wave * 16 + quad * 4 + r;
            u16* orow = o + ((size_t)b * 1024 + n) * 512 + h * 32;
            orow[l16]      = f2bf(o_acc[g][0][r] * inv);
            orow[16 + l16] = f2bf(o_acc[g][1][r] * inv);
        }
}

extern "C" void kernel_launch(void* const* d_in, const int* in_sizes, int n_in,
                              void* d_out, int out_size, void* d_ws, size_t ws_size,
                              hipStream_t stream) {
    const void* x      = d_in[0];  // (8192,512)
    const void* qkv_w  = d_in[1];  // (1536,512)
    const void* qkv_b  = d_in[2];  // (1536)
    const void* rpb    = d_in[3];  // (16,63,63)
    const void* proj_w = d_in[4];  // (512,512)
    const void* proj_b = d_in[5];  // (512)

    // ws layout (u16 units), ~26.3 MiB. xbf aliases ao (disjoint lifetimes).
    // q lives in d_out (consumed by attn before proj GEMM overwrites d_out).
    u16* ws    = (u16*)d_ws;
    u16* kb    = ws;                   // [b][h][t][c]  8 MiB
    u16* vb    = ws + 4194304;         // [b][h][c][t]  8 MiB
    u16* xbf   = ws + 8388608;         // (8192,512)    8 MiB (== ao)
    u16* ao    = xbf;
    u16* qwbf  = ws + 12582912;        // 1.5 MiB
    u16* pwbf  = ws + 13369344;        // 0.5 MiB
    u16* qbbf  = ws + 13631488;
    u16* pbbf  = ws + 13633024;
    float* rpl2e = (float*)(ws + 13633536);  // 254 KiB
    u16* qb    = (u16*)d_out;          // [b][h][t][c]  8 MiB

    convert_inputs<<<1024, 256, 0, stream>>>(x, qkv_w, qkv_b, proj_w, proj_b, rpb,
                                             xbf, qwbf, qbbf, pwbf, pbbf, rpl2e);

    // QKV GEMM, TRANSPOSED: rows = channels (A = qkv_w), cols = tokens (W-arg = x)
    dim3 g1(8192 / 128, 1536 / 128);
    gemm_bt<1, 128><<<g1, 256, 0, stream>>>(qwbf, xbf, qbbf, nullptr, qb, kb, vb, x, 8192, 512);

    // attention: XCD-swizzled grid (x=h fixes XCD class per (b,h))
    dim3 g2(16, 8, 8);
    attn<<<g2, 256, 0, stream>>>(qb, kb, vb, rpl2e, ao);

    dim3 g3(512 / 128, 8192 / 64);
    gemm_bt<0, 64><<<g3, 256, 0, stream>>>(ao, pwbf, pbbf, d_out, nullptr, nullptr, nullptr, x, 512, 512);
}

// Round 2
// 153.042 us; speedup vs baseline: 1.0681x; 1.0681x over previous
//
#include <hip/hip_runtime.h>

typedef __bf16 bf16x8 __attribute__((ext_vector_type(8)));
typedef float f32x4 __attribute__((ext_vector_type(4)));
typedef unsigned short u16;
typedef unsigned int u32;

__device__ __forceinline__ float bf2f(u16 v) {
    union { unsigned u; float f; } x; x.u = ((unsigned)v) << 16; return x.f;
}
__device__ __forceinline__ u16 f2bf(float f) {
    union { float f; unsigned u; } x; x.f = f;
    unsigned r = x.u + 0x7fffu + ((x.u >> 16) & 1u);
    return (u16)(r >> 16);
}

// Runtime dtype probe (HW-verified r4): f32 buffer -> low u16 of each word is
// mantissa bits -> bf16-exponent ~uniform (~44% >= 0x90); bf16 buffer -> 0 hits.
__device__ __forceinline__ bool probe_is_f32(const void* xp) {
    const unsigned* p = (const unsigned*)xp;
    int hits = 0;
#pragma unroll
    for (int i = 0; i < 32; i++) {
        const unsigned e = (p[i] >> 7) & 0xffu;
        hits += (e >= 0x90u) ? 1 : 0;
    }
    return hits > 3;
}

__device__ __forceinline__ float ld1(const void* p, size_t i, bool isf32) {
    return isf32 ? ((const float*)p)[i] : bf2f(((const u16*)p)[i]);
}

// Async global->LDS DMA, 16B/lane; LDS dest = wave-uniform base + lane*16.
__device__ __forceinline__ void gl2lds16(const void* g, void* l) {
    __builtin_amdgcn_global_load_lds(
        (const __attribute__((address_space(1))) u32*)g,
        (__attribute__((address_space(3))) u32*)l, 16, 0, 0);
}

// One-shot input normalization: everything -> bf16, rpb -> f32 * log2(e).
__global__ __launch_bounds__(256)
void convert_inputs(const void* __restrict__ x, const void* __restrict__ qw,
                    const void* __restrict__ qb, const void* __restrict__ pw,
                    const void* __restrict__ pb, const void* __restrict__ rp,
                    u16* __restrict__ xbf, u16* __restrict__ qwbf,
                    u16* __restrict__ qbbf, u16* __restrict__ pwbf,
                    u16* __restrict__ pbbf, float* __restrict__ rpl2e)
{
    const bool isf32 = probe_is_f32(x);
    const int gid = blockIdx.x * 256 + threadIdx.x;
    const int gsz = gridDim.x * 256;

    struct Seg { const void* s; u16* d; int n; };
    const Seg segs[5] = {{x, xbf, 4194304}, {qw, qwbf, 786432}, {pw, pwbf, 262144},
                         {qb, qbbf, 1536}, {pb, pbbf, 512}};
    for (int t = 0; t < 5; t++) {
        const int n4 = segs[t].n >> 2;
        if (isf32) {
            const f32x4* s = (const f32x4*)segs[t].s;
            for (int i = gid; i < n4; i += gsz) {
                f32x4 v = s[i];
                ushort4 o;
                o.x = f2bf(v[0]); o.y = f2bf(v[1]); o.z = f2bf(v[2]); o.w = f2bf(v[3]);
                *(ushort4*)(segs[t].d + i * 4) = o;
            }
        } else {
            const ushort4* s = (const ushort4*)segs[t].s;
            for (int i = gid; i < n4; i += gsz) *(ushort4*)(segs[t].d + i * 4) = s[i];
        }
    }
    for (int i = gid; i < 63504; i += gsz)
        rpl2e[i] = ld1(rp, i, isf32) * 1.4426950408889634f;
}

// GEMM D = A(MxK) @ W(NoutxK)^T + bias, pure bf16, fp32 accum. BMx128 tile.
// K-loop unrolled x2 with TWO independent BK=32 LDS buffers per operand:
// one barrier-pair per 64 of K (halves the m97-structure barrier drains)
// while keeping the proven conflict-free stride-32 per-buffer layout.
// MODE 0: bias[col]; dual-dtype row-major store to d_out (probe decides).
// MODE 1 (TRANSPOSED QKV): A = qkv_w (rows = channels), W-arg = x (rows =
//   tokens). D[ch][tok]. bias[row]. which = m0>>9 block-uniform.
//   q,k -> [b][h][t][c] packed ushort4; v -> [b][h][c][t] scalar.
template<int MODE, int BM>
__global__ __launch_bounds__(256, MODE == 1 ? 3 : 4)
void gemm_bt(const u16* __restrict__ A, const u16* __restrict__ W,
             const u16* __restrict__ bias, void* __restrict__ out,
             u16* __restrict__ q_out, u16* __restrict__ k_out, u16* __restrict__ v_out,
             const void* __restrict__ probe, int Nout, int K)
{
    __shared__ __align__(16) u16 As[2][BM * 32];
    __shared__ __align__(16) u16 Ws[2][128 * 32];
    constexpr int RW = BM / 32;            // A-frags per wave

    const int tid  = threadIdx.x;
    const int lane = tid & 63;
    const int wave = tid >> 6;
    const int quad = lane >> 4;
    const int l16  = lane & 15;
    const int m0 = blockIdx.y * BM;
    const int n0 = blockIdx.x * 128;
    const int wm = (wave >> 1) * (BM / 2);
    const int wn = (wave & 1) * 64;

    f32x4 acc[RW][4] = {};

    for (int k0 = 0; k0 < K; k0 += 64) {
        __syncthreads();
        for (int u = 0; u < 2; u++) {
            {
                const u16* g = A + (size_t)(m0 + wave * 16 + (lane >> 2)) * K
                                 + k0 + u * 32 + (lane & 3) * 8;
                u16* l = As[u] + wave * 16 * 32;
                for (int p = 0; p < BM / 64; p++) gl2lds16(g + (size_t)p * 64 * K, l + p * 64 * 32);
            }
            {
                const u16* g = W + (size_t)(n0 + wave * 16 + (lane >> 2)) * K
                                 + k0 + u * 32 + (lane & 3) * 8;
                u16* l = Ws[u] + wave * 16 * 32;
                for (int p = 0; p < 2; p++) gl2lds16(g + (size_t)p * 64 * K, l + p * 64 * 32);
            }
        }
        __syncthreads();

        for (int u = 0; u < 2; u++) {
            bf16x8 af[RW], wf[4];
            for (int i = 0; i < RW; i++)
                af[i] = *(const bf16x8*)(As[u] + (wm + i * 16 + l16) * 32 + quad * 8);
            for (int j = 0; j < 4; j++)
                wf[j] = *(const bf16x8*)(Ws[u] + (wn + j * 16 + l16) * 32 + quad * 8);
            for (int i = 0; i < RW; i++)
                for (int j = 0; j < 4; j++)
                    acc[i][j] = __builtin_amdgcn_mfma_f32_16x16x32_bf16(af[i], wf[j], acc[i][j], 0, 0, 0);
        }
    }

    // D layout per 16x16 tile: row = quad*4 + r, col = l16
    if (MODE == 0) {
        const bool isf32 = probe_is_f32(probe);
        for (int j = 0; j < 4; j++) {
            const int col = n0 + wn + j * 16 + l16;
            const float bv = bf2f(bias[col]);
            for (int i = 0; i < RW; i++) {
                const int rbase = m0 + wm + i * 16 + quad * 4;
                for (int r = 0; r < 4; r++) {
                    const float val = acc[i][j][r] + bv;
                    if (isf32) ((float*)out)[(size_t)(rbase + r) * Nout + col] = val;
                    else       ((u16*)out)[(size_t)(rbase + r) * Nout + col]  = f2bf(val);
                }
            }
        }
    } else {
        const int which = m0 >> 9;       // block-uniform (m0 128-aligned)
        float bv[RW][4];
        for (int i = 0; i < RW; i++) {
            const int row4 = m0 + wm + i * 16 + quad * 4;
            for (int r = 0; r < 4; r++) bv[i][r] = bf2f(bias[row4 + r]);
        }
        for (int j = 0; j < 4; j++) {
            const int tok = n0 + wn + j * 16 + l16;
            const int bi = tok >> 10, t = tok & 1023;
            for (int i = 0; i < RW; i++) {
                const int row4 = m0 + wm + i * 16 + quad * 4;
                const int h = (row4 >> 5) & 15;
                const int c = row4 & 31;
                if (which == 2) {        // v: [b][h][c][t]
                    for (int r = 0; r < 4; r++)
                        v_out[((size_t)(bi * 16 + h) * 32 + c + r) * 1024 + t] =
                            f2bf(acc[i][j][r] + bv[i][r]);
                } else {                 // q,k: [b][h][t][c], 8B packed
                    u16* dst = which ? k_out : q_out;
                    ushort4 pk;
                    pk.x = f2bf(acc[i][j][0] + bv[i][0]);
                    pk.y = f2bf(acc[i][j][1] + bv[i][1]);
                    pk.z = f2bf(acc[i][j][2] + bv[i][2]);
                    pk.w = f2bf(acc[i][j][3] + bv[i][3]);
                    *(ushort4*)(dst + ((size_t)(bi * 16 + h) * 1024 + t) * 32 + c) = pk;
                }
            }
        }
    }
}

// Flash attention, S^T formulation, offset-free softmax, MFMA denominator,
// zero shuffles (validated r8). Q frags direct from global; V frags hoisted.
// XCD-SWIZZLED GRID (r10: FETCH 70 MB vs 25 MB working set = cross-XCD K/V
// re-fetch): grid (16,8,8) x=h,y=qt,z=b -> linear ids of the 8 qt-blocks of a
// (b,h) differ by 16 -> same XCD (id%8=h%8) -> K/V (128 KB) served from that
// XCD's L2; 16 (b,h)/XCD = 2 MB < 4 MB L2. All 1024 blocks co-resident (4/CU).
// Ps stride 72 (>=64 required; r7's 40 aliased rows). TQ=128/block,
// double-buffered K/V register prefetch, 1 barrier/kt.
//
// r11 POST-MORTEM (kept as a constraint): K/V fragments direct-from-global
// REGRESSED 44->56us (MfmaUtil 15%, latency-bound). Grid caps residency at
// 4 blocks/CU, so freed LDS buys no occupancy; vf direct loads have 2KB lane
// stride (64 separate L2 transactions/wave). The staged+prefetch pipeline is
// the right skeleton. r12: staged skeleton + T5 setprio around MFMA clusters
// (m191: attn +4-7%; independent blocks drift out of phase on each CU).
__global__ __launch_bounds__(256, 4)
void attn(const u16* __restrict__ q, const u16* __restrict__ k,
          const u16* __restrict__ vt, const float* __restrict__ rpl2e,
          u16* __restrict__ o)
{
    __shared__ __align__(16) u16 Ks[2][64 * 40];
    __shared__ __align__(16) u16 Vt[2][32 * 72];
    __shared__ __align__(16) u16 Ps[4][16 * 72];
    __shared__ float biasS[35 * 63];

    const int tid  = threadIdx.x;
    const int lane = tid & 63;
    const int wave = tid >> 6;
    const int quad = lane >> 4;
    const int l16  = lane & 15;

    const int h  = blockIdx.x;   // 16 heads (fastest -> fixes XCD class)
    const int qt = blockIdx.y;   // 8 q-tiles of 128
    const int b  = blockIdx.z;
    const int n0 = qt * 128;
    const size_t base = ((size_t)(b * 16 + h)) * 32768;  // q,k [t][c]; vt [c][t]

    // ---- prologue: bias region, kt=0 K/V, Q frags from global ----
    {
        const int row0 = 28 - 4 * qt;
        for (int idx = tid; idx < 2205; idx += 256)
            biasS[idx] = rpl2e[(size_t)h * 3969 + (size_t)(row0 + idx / 63) * 63 + idx % 63];
    }
    uint4 kreg = *(const uint4*)(k + base + (size_t)(tid >> 2) * 32 + (tid & 3) * 8);
    uint4 vreg = *(const uint4*)(vt + base + (size_t)(tid >> 3) * 1024 + (tid & 7) * 8);
    *(uint4*)(Ks[0] + (tid >> 2) * 40 + (tid & 3) * 8) = kreg;
    *(uint4*)(Vt[0] + (tid >> 3) * 72 + (tid & 7) * 8) = vreg;

    bf16x8 qf[2];
    for (int g = 0; g < 2; g++) {
        union { uint4 u; bf16x8 f; } cv;
        cv.u = *(const uint4*)(q + base + (size_t)(n0 + g * 64 + wave * 16 + l16) * 32 + quad * 8);
        qf[g] = cv.f;
    }
    __syncthreads();

    bf16x8 ones;
    for (int i = 0; i < 8; i++) ones[i] = (__bf16)1.0f;

    // o_acc[g][0..1] = O columns ct*16+l16; o_acc[g][2] = denominator l
    f32x4 o_acc[2][3] = {};
    const int bn = (wave & 1) * 16 + l16;   // n & 31 (group-invariant)
    const float SC = 0.25503485724582146f;  // d^-0.5 * log2(e)
    u16* pw = Ps[wave];

    for (int kt = 0; kt < 16; kt++) {
        const int cur = kt & 1;
        if (kt < 15) {   // prefetch next K/V tile into regs (in flight during compute)
            const int mn = (kt + 1) * 64;
            kreg = *(const uint4*)(k + base + (size_t)(mn + (tid >> 2)) * 32 + (tid & 3) * 8);
            vreg = *(const uint4*)(vt + base + (size_t)(tid >> 3) * 1024 + mn + (tid & 7) * 8);
        }

        bf16x8 kf[4];
        for (int j = 0; j < 4; j++)
            kf[j] = *(const bf16x8*)(Ks[cur] + (j * 16 + l16) * 40 + quad * 8);
        bf16x8 vf[2][2];                    // V frags: g-invariant, load once
        for (int kc = 0; kc < 2; kc++)
            for (int ct = 0; ct < 2; ct++)
                vf[kc][ct] = *(const bf16x8*)(Vt[cur] + (ct * 16 + l16) * 72 + kc * 32 + quad * 8);

        for (int g = 0; g < 2; g++) {
            // S^T tile: D col n=l16, row m_loc = j*16 + quad*4 + r
            f32x4 s4[4];
            const f32x4 zero = {};
            __builtin_amdgcn_s_setprio(1);
            for (int j = 0; j < 4; j++)
                s4[j] = __builtin_amdgcn_mfma_f32_16x16x32_bf16(kf[j], qf[g], zero, 0, 0, 0);
            __builtin_amdgcn_s_setprio(0);

            const int rbase = 2 * kt - (wave >> 1) - 2 * g + 3;
            for (int j = 0; j < 4; j++) {
                const float* brow = biasS + (rbase + (j >> 1)) * 63
                                   + ((j & 1) * 16 + quad * 4) - bn + 31;
                ushort4 pk;
                u16* pks = (u16*)&pk;
                for (int r = 0; r < 4; r++) {
                    const float pv = __builtin_amdgcn_exp2f(s4[j][r] * SC + brow[r]);
                    union { __bf16 b; u16 u; } cv; cv.b = (__bf16)pv;
                    pks[r] = cv.u;
                }
                // P[n=l16][m = j*16 + quad*4 + r] -> one 8B store
                *(ushort4*)(pw + l16 * 72 + j * 16 + quad * 4) = pk;
            }

            // O += P·V and l += P·1 (in-wave DS ordering covers write->read)
            __builtin_amdgcn_s_setprio(1);
            for (int kc = 0; kc < 2; kc++) {
                const bf16x8 pa = *(const bf16x8*)(pw + l16 * 72 + kc * 32 + quad * 8);
                for (int ct = 0; ct < 2; ct++)
                    o_acc[g][ct] = __builtin_amdgcn_mfma_f32_16x16x32_bf16(pa, vf[kc][ct], o_acc[g][ct], 0, 0, 0);
                o_acc[g][2] = __builtin_amdgcn_mfma_f32_16x16x32_bf16(pa, ones, o_acc[g][2], 0, 0, 0);
            }
            __builtin_amdgcn_s_setprio(0);
        }

        if (kt < 15) {   // write prefetched tile to back buffer
            *(uint4*)(Ks[cur ^ 1] + (tid >> 2) * 40 + (tid & 3) * 8) = kreg;
            *(uint4*)(Vt[cur ^ 1] + (tid >> 3) * 72 + (tid & 7) * 8) = vreg;
        }
        __syncthreads();
    }

    for (int g = 0; g < 2; g++)
        for (int r = 0; r < 4; r++) {
            const float inv = __builtin_amdgcn_rcpf(o_acc[g][2][r]);
            const int n = n0 + g * 64 + wave * 16 + quad * 4 + r;
            u16* orow = o + ((size_t)b * 1024 + n) * 512 + h * 32;
            orow[l16]      = f2bf(o_acc[g][0][r] * inv);
            orow[16 + l16] = f2bf(o_acc[g][1][r] * inv);
        }
}

extern "C" void kernel_launch(void* const* d_in, const int* in_sizes, int n_in,
                              void* d_out, int out_size, void* d_ws, size_t ws_size,
                              hipStream_t stream) {
    const void* x      = d_in[0];  // (8192,512)
    const void* qkv_w  = d_in[1];  // (1536,512)
    const void* qkv_b  = d_in[2];  // (1536)
    const void* rpb    = d_in[3];  // (16,63,63)
    const void* proj_w = d_in[4];  // (512,512)
    const void* proj_b = d_in[5];  // (512)

    // ws layout (u16 units), ~26.3 MiB. xbf aliases ao (disjoint lifetimes).
    // q lives in d_out (consumed by attn before proj GEMM overwrites d_out).
    u16* ws    = (u16*)d_ws;
    u16* kb    = ws;                   // [b][h][t][c]  8 MiB
    u16* vb    = ws + 4194304;         // [b][h][c][t]  8 MiB
    u16* xbf   = ws + 8388608;         // (8192,512)    8 MiB (== ao)
    u16* ao    = xbf;
    u16* qwbf  = ws + 12582912;        // 1.5 MiB
    u16* pwbf  = ws + 13369344;        // 0.5 MiB
    u16* qbbf  = ws + 13631488;
    u16* pbbf  = ws + 13633024;
    float* rpl2e = (float*)(ws + 13633536);  // 254 KiB
    u16* qb    = (u16*)d_out;          // [b][h][t][c]  8 MiB

    convert_inputs<<<1024, 256, 0, stream>>>(x, qkv_w, qkv_b, proj_w, proj_b, rpb,
                                             xbf, qwbf, qbbf, pwbf, pbbf, rpl2e);

    // QKV GEMM, TRANSPOSED: rows = channels (A = qkv_w), cols = tokens (W-arg = x)
    dim3 g1(8192 / 128, 1536 / 128);
    gemm_bt<1, 128><<<g1, 256, 0, stream>>>(qwbf, xbf, qbbf, nullptr, qb, kb, vb, x, 8192, 512);

    // attention: XCD-swizzled grid (x=h fixes XCD class per (b,h))
    dim3 g2(16, 8, 8);
    attn<<<g2, 256, 0, stream>>>(qb, kb, vb, rpl2e, ao);

    dim3 g3(512 / 128, 8192 / 64);
    gemm_bt<0, 64><<<g3, 256, 0, stream>>>(ao, pwbf, pbbf, d_out, nullptr, nullptr, nullptr, x, 512, 512);
}

// Round 3
// 151.506 us; speedup vs baseline: 1.0789x; 1.0101x over previous
//
#include <hip/hip_runtime.h>

typedef __bf16 bf16x8 __attribute__((ext_vector_type(8)));
typedef float f32x4 __attribute__((ext_vector_type(4)));
typedef unsigned short u16;
typedef unsigned int u32;

__device__ __forceinline__ float bf2f(u16 v) {
    union { unsigned u; float f; } x; x.u = ((unsigned)v) << 16; return x.f;
}
__device__ __forceinline__ u16 f2bf(float f) {
    union { float f; unsigned u; } x; x.f = f;
    unsigned r = x.u + 0x7fffu + ((x.u >> 16) & 1u);
    return (u16)(r >> 16);
}

// Runtime dtype probe (HW-verified r4): f32 buffer -> low u16 of each word is
// mantissa bits -> bf16-exponent ~uniform (~44% >= 0x90); bf16 buffer -> 0 hits.
__device__ __forceinline__ bool probe_is_f32(const void* xp) {
    const unsigned* p = (const unsigned*)xp;
    int hits = 0;
#pragma unroll
    for (int i = 0; i < 32; i++) {
        const unsigned e = (p[i] >> 7) & 0xffu;
        hits += (e >= 0x90u) ? 1 : 0;
    }
    return hits > 3;
}

__device__ __forceinline__ float ld1(const void* p, size_t i, bool isf32) {
    return isf32 ? ((const float*)p)[i] : bf2f(((const u16*)p)[i]);
}

// Async global->LDS DMA, 16B/lane; LDS dest = wave-uniform base + lane*16.
__device__ __forceinline__ void gl2lds16(const void* g, void* l) {
    __builtin_amdgcn_global_load_lds(
        (const __attribute__((address_space(1))) u32*)g,
        (__attribute__((address_space(3))) u32*)l, 16, 0, 0);
}

// One-shot input normalization: everything -> bf16, rpb -> f32 * log2(e).
__global__ __launch_bounds__(256)
void convert_inputs(const void* __restrict__ x, const void* __restrict__ qw,
                    const void* __restrict__ qb, const void* __restrict__ pw,
                    const void* __restrict__ pb, const void* __restrict__ rp,
                    u16* __restrict__ xbf, u16* __restrict__ qwbf,
                    u16* __restrict__ qbbf, u16* __restrict__ pwbf,
                    u16* __restrict__ pbbf, float* __restrict__ rpl2e)
{
    const bool isf32 = probe_is_f32(x);
    const int gid = blockIdx.x * 256 + threadIdx.x;
    const int gsz = gridDim.x * 256;

    struct Seg { const void* s; u16* d; int n; };
    const Seg segs[5] = {{x, xbf, 4194304}, {qw, qwbf, 786432}, {pw, pwbf, 262144},
                         {qb, qbbf, 1536}, {pb, pbbf, 512}};
    for (int t = 0; t < 5; t++) {
        const int n4 = segs[t].n >> 2;
        if (isf32) {
            const f32x4* s = (const f32x4*)segs[t].s;
            for (int i = gid; i < n4; i += gsz) {
                f32x4 v = s[i];
                ushort4 o;
                o.x = f2bf(v[0]); o.y = f2bf(v[1]); o.z = f2bf(v[2]); o.w = f2bf(v[3]);
                *(ushort4*)(segs[t].d + i * 4) = o;
            }
        } else {
            const ushort4* s = (const ushort4*)segs[t].s;
            for (int i = gid; i < n4; i += gsz) *(ushort4*)(segs[t].d + i * 4) = s[i];
        }
    }
    for (int i = gid; i < 63504; i += gsz)
        rpl2e[i] = ld1(rp, i, isf32) * 1.4426950408889634f;
}

// GEMM D = A(MxK) @ W(NoutxK)^T + bias, pure bf16, fp32 accum. BMx128 tile.
// K-loop unrolled x2 with TWO independent BK=32 LDS buffers per operand:
// one barrier-pair per 64 of K (halves the m97-structure barrier drains)
// while keeping the proven conflict-free stride-32 per-buffer layout.
// MODE 0: bias[col]; dual-dtype row-major store to d_out (probe decides).
// MODE 1 (TRANSPOSED QKV): A = qkv_w (rows = channels), W-arg = x (rows =
//   tokens). D[ch][tok]. bias[row]. which = m0>>9 block-uniform.
//   q,k -> [b][h][t][c] packed ushort4; v -> [b][h][c][t] scalar.
template<int MODE, int BM>
__global__ __launch_bounds__(256, MODE == 1 ? 3 : 4)
void gemm_bt(const u16* __restrict__ A, const u16* __restrict__ W,
             const u16* __restrict__ bias, void* __restrict__ out,
             u16* __restrict__ q_out, u16* __restrict__ k_out, u16* __restrict__ v_out,
             const void* __restrict__ probe, int Nout, int K)
{
    __shared__ __align__(16) u16 As[2][BM * 32];
    __shared__ __align__(16) u16 Ws[2][128 * 32];
    constexpr int RW = BM / 32;            // A-frags per wave

    const int tid  = threadIdx.x;
    const int lane = tid & 63;
    const int wave = tid >> 6;
    const int quad = lane >> 4;
    const int l16  = lane & 15;
    const int m0 = blockIdx.y * BM;
    const int n0 = blockIdx.x * 128;
    const int wm = (wave >> 1) * (BM / 2);
    const int wn = (wave & 1) * 64;

    f32x4 acc[RW][4] = {};

    for (int k0 = 0; k0 < K; k0 += 64) {
        __syncthreads();
        for (int u = 0; u < 2; u++) {
            {
                const u16* g = A + (size_t)(m0 + wave * 16 + (lane >> 2)) * K
                                 + k0 + u * 32 + (lane & 3) * 8;
                u16* l = As[u] + wave * 16 * 32;
                for (int p = 0; p < BM / 64; p++) gl2lds16(g + (size_t)p * 64 * K, l + p * 64 * 32);
            }
            {
                const u16* g = W + (size_t)(n0 + wave * 16 + (lane >> 2)) * K
                                 + k0 + u * 32 + (lane & 3) * 8;
                u16* l = Ws[u] + wave * 16 * 32;
                for (int p = 0; p < 2; p++) gl2lds16(g + (size_t)p * 64 * K, l + p * 64 * 32);
            }
        }
        __syncthreads();

        for (int u = 0; u < 2; u++) {
            bf16x8 af[RW], wf[4];
            for (int i = 0; i < RW; i++)
                af[i] = *(const bf16x8*)(As[u] + (wm + i * 16 + l16) * 32 + quad * 8);
            for (int j = 0; j < 4; j++)
                wf[j] = *(const bf16x8*)(Ws[u] + (wn + j * 16 + l16) * 32 + quad * 8);
            for (int i = 0; i < RW; i++)
                for (int j = 0; j < 4; j++)
                    acc[i][j] = __builtin_amdgcn_mfma_f32_16x16x32_bf16(af[i], wf[j], acc[i][j], 0, 0, 0);
        }
    }

    // D layout per 16x16 tile: row = quad*4 + r, col = l16
    if (MODE == 0) {
        const bool isf32 = probe_is_f32(probe);
        for (int j = 0; j < 4; j++) {
            const int col = n0 + wn + j * 16 + l16;
            const float bv = bf2f(bias[col]);
            for (int i = 0; i < RW; i++) {
                const int rbase = m0 + wm + i * 16 + quad * 4;
                for (int r = 0; r < 4; r++) {
                    const float val = acc[i][j][r] + bv;
                    if (isf32) ((float*)out)[(size_t)(rbase + r) * Nout + col] = val;
                    else       ((u16*)out)[(size_t)(rbase + r) * Nout + col]  = f2bf(val);
                }
            }
        }
    } else {
        const int which = m0 >> 9;       // block-uniform (m0 128-aligned)
        float bv[RW][4];
        for (int i = 0; i < RW; i++) {
            const int row4 = m0 + wm + i * 16 + quad * 4;
            for (int r = 0; r < 4; r++) bv[i][r] = bf2f(bias[row4 + r]);
        }
        for (int j = 0; j < 4; j++) {
            const int tok = n0 + wn + j * 16 + l16;
            const int bi = tok >> 10, t = tok & 1023;
            for (int i = 0; i < RW; i++) {
                const int row4 = m0 + wm + i * 16 + quad * 4;
                const int h = (row4 >> 5) & 15;
                const int c = row4 & 31;
                if (which == 2) {        // v: [b][h][c][t]
                    for (int r = 0; r < 4; r++)
                        v_out[((size_t)(bi * 16 + h) * 32 + c + r) * 1024 + t] =
                            f2bf(acc[i][j][r] + bv[i][r]);
                } else {                 // q,k: [b][h][t][c], 8B packed
                    u16* dst = which ? k_out : q_out;
                    ushort4 pk;
                    pk.x = f2bf(acc[i][j][0] + bv[i][0]);
                    pk.y = f2bf(acc[i][j][1] + bv[i][1]);
                    pk.z = f2bf(acc[i][j][2] + bv[i][2]);
                    pk.w = f2bf(acc[i][j][3] + bv[i][3]);
                    *(ushort4*)(dst + ((size_t)(bi * 16 + h) * 1024 + t) * 32 + c) = pk;
                }
            }
        }
    }
}

// Flash attention, S^T formulation, offset-free softmax, MFMA denominator,
// zero shuffles (validated r8). Q frags direct from global; V frags hoisted.
// XCD-SWIZZLED GRID (r10): grid (16,8,8) x=h,y=qt,z=b -> 8 qt-blocks of a
// (b,h) land on one XCD (id%8=h%8) -> K/V served from that XCD's L2.
// Ps stride 72. TQ=128/block, double-buffered K/V register prefetch,
// 1 barrier/kt.
//
// r11: K/V direct-from-global REGRESSED (latency-bound at 4 blocks/CU).
// r12: T5 setprio NEUTRAL-NEGATIVE (4-wave lockstep = m190 null) -> removed.
// r13 (this round): bias gather -> sliding REGISTER WINDOW. r12 counters:
// LDS unit ~90% saturated, bias = largest slice (~32 scalar b32/kt/wave).
// Rows advance by 2/kt, per-lane cols are kt-invariant -> hold 4 rows x 8
// cols in regs (X0/X1/Y0/Y1), load only 2 new rows/kt from TRANSPOSED
// biasT[col][row] (stride 37, coprime banks) -> adjacent rows = one
// ds_read2_b32 per col: 8 DS instr/kt/wave replaces ~32.
__global__ __launch_bounds__(256, 4)
void attn(const u16* __restrict__ q, const u16* __restrict__ k,
          const u16* __restrict__ vt, const float* __restrict__ rpl2e,
          u16* __restrict__ o)
{
    __shared__ __align__(16) u16 Ks[2][64 * 40];
    __shared__ __align__(16) u16 Vt[2][32 * 72];
    __shared__ __align__(16) u16 Ps[4][16 * 72];
    __shared__ float biasT[63 * 37];   // [col][row], 35 rows + 2 pad

    const int tid  = threadIdx.x;
    const int lane = tid & 63;
    const int wave = tid >> 6;
    const int quad = lane >> 4;
    const int l16  = lane & 15;

    const int h  = blockIdx.x;   // 16 heads (fastest -> fixes XCD class)
    const int qt = blockIdx.y;   // 8 q-tiles of 128
    const int b  = blockIdx.z;
    const int n0 = qt * 128;
    const size_t base = ((size_t)(b * 16 + h)) * 32768;  // q,k [t][c]; vt [c][t]

    // ---- prologue: bias region (transposed), kt=0 K/V, Q frags ----
    {
        const int row0 = 28 - 4 * qt;
        for (int idx = tid; idx < 2205; idx += 256) {
            const int rr = idx / 63, cc = idx % 63;
            biasT[cc * 37 + rr] =
                rpl2e[(size_t)h * 3969 + (size_t)(row0 + rr) * 63 + cc];
        }
    }
    uint4 kreg = *(const uint4*)(k + base + (size_t)(tid >> 2) * 32 + (tid & 3) * 8);
    uint4 vreg = *(const uint4*)(vt + base + (size_t)(tid >> 3) * 1024 + (tid & 7) * 8);
    *(uint4*)(Ks[0] + (tid >> 2) * 40 + (tid & 3) * 8) = kreg;
    *(uint4*)(Vt[0] + (tid >> 3) * 72 + (tid & 7) * 8) = vreg;

    bf16x8 qf[2];
    for (int g = 0; g < 2; g++) {
        union { uint4 u; bf16x8 f; } cv;
        cv.u = *(const uint4*)(q + base + (size_t)(n0 + g * 64 + wave * 16 + l16) * 32 + quad * 8);
        qf[g] = cv.f;
    }
    __syncthreads();

    bf16x8 ones;
    for (int i = 0; i < 8; i++) ones[i] = (__bf16)1.0f;

    // o_acc[g][0..1] = O columns ct*16+l16; o_acc[g][2] = denominator l
    f32x4 o_acc[2][3] = {};
    const int bn = (wave & 1) * 16 + l16;   // n & 31 (group-invariant)
    const int w2 = wave >> 1;
    const float SC = 0.25503485724582146f;  // d^-0.5 * log2(e)
    u16* pw = Ps[wave];

    // Bias register window. Rows as function of kt: B = 2*kt - w2 + 1.
    // g=1 uses rows (B, B+1) = X0/X1; g=0 uses rows (B+2, B+3) = Y0/Y1.
    // Per-lane col for slot ci: c = cb + (ci>>2)*16 + (ci&3), kt-invariant.
    const int cb = quad * 4 + 31 - bn;
    float X0[8], X1[8], Y0[8], Y1[8];
#pragma unroll
    for (int ci = 0; ci < 8; ci++) {
        const int c37 = (cb + (ci >> 2) * 16 + (ci & 3)) * 37;
        X0[ci] = biasT[c37 + (1 - w2)];
        X1[ci] = biasT[c37 + (2 - w2)];
        Y0[ci] = biasT[c37 + (3 - w2)];
        Y1[ci] = biasT[c37 + (4 - w2)];
    }

    for (int kt = 0; kt < 16; kt++) {
        const int cur = kt & 1;
        if (kt < 15) {   // prefetch next K/V tile into regs (in flight during compute)
            const int mn = (kt + 1) * 64;
            kreg = *(const uint4*)(k + base + (size_t)(mn + (tid >> 2)) * 32 + (tid & 3) * 8);
            vreg = *(const uint4*)(vt + base + (size_t)(tid >> 3) * 1024 + mn + (tid & 7) * 8);
        }

        bf16x8 kf[4];
#pragma unroll
        for (int j = 0; j < 4; j++)
            kf[j] = *(const bf16x8*)(Ks[cur] + (j * 16 + l16) * 40 + quad * 8);
        bf16x8 vf[2][2];                    // V frags: g-invariant, load once
#pragma unroll
        for (int kc = 0; kc < 2; kc++)
#pragma unroll
            for (int ct = 0; ct < 2; ct++)
                vf[kc][ct] = *(const bf16x8*)(Vt[cur] + (ct * 16 + l16) * 72 + kc * 32 + quad * 8);

#pragma unroll
        for (int g = 0; g < 2; g++) {
            // S^T tile: D col n=l16, row m_loc = j*16 + quad*4 + r
            f32x4 s4[4];
            const f32x4 zero = {};
#pragma unroll
            for (int j = 0; j < 4; j++)
                s4[j] = __builtin_amdgcn_mfma_f32_16x16x32_bf16(kf[j], qf[g], zero, 0, 0, 0);

#pragma unroll
            for (int j = 0; j < 4; j++) {
                ushort4 pk;
                u16* pks = (u16*)&pk;
#pragma unroll
                for (int r = 0; r < 4; r++) {
                    const int ci = (j & 1) * 4 + r;
                    const float bval = (j >> 1) ? (g ? X1[ci] : Y1[ci])
                                                : (g ? X0[ci] : Y0[ci]);
                    const float pv = __builtin_amdgcn_exp2f(s4[j][r] * SC + bval);
                    union { __bf16 b; u16 u; } cv; cv.b = (__bf16)pv;
                    pks[r] = cv.u;
                }
                // P[n=l16][m = j*16 + quad*4 + r] -> one 8B store
                *(ushort4*)(pw + l16 * 72 + j * 16 + quad * 4) = pk;
            }

            // O += P·V and l += P·1 (in-wave DS ordering covers write->read)
#pragma unroll
            for (int kc = 0; kc < 2; kc++) {
                const bf16x8 pa = *(const bf16x8*)(pw + l16 * 72 + kc * 32 + quad * 8);
#pragma unroll
                for (int ct = 0; ct < 2; ct++)
                    o_acc[g][ct] = __builtin_amdgcn_mfma_f32_16x16x32_bf16(pa, vf[kc][ct], o_acc[g][ct], 0, 0, 0);
                o_acc[g][2] = __builtin_amdgcn_mfma_f32_16x16x32_bf16(pa, ones, o_acc[g][2], 0, 0, 0);
            }
        }

        if (kt < 15) {
            // rotate bias window: X <- Y, load rows (B+4, B+5) into Y
#pragma unroll
            for (int ci = 0; ci < 8; ci++) { X0[ci] = Y0[ci]; X1[ci] = Y1[ci]; }
            const int nr = 2 * kt - w2 + 5;
#pragma unroll
            for (int ci = 0; ci < 8; ci++) {
                const int c37 = (cb + (ci >> 2) * 16 + (ci & 3)) * 37;
                Y0[ci] = biasT[c37 + nr];
                Y1[ci] = biasT[c37 + nr + 1];
            }
            // write prefetched K/V tile to back buffer
            *(uint4*)(Ks[cur ^ 1] + (tid >> 2) * 40 + (tid & 3) * 8) = kreg;
            *(uint4*)(Vt[cur ^ 1] + (tid >> 3) * 72 + (tid & 7) * 8) = vreg;
        }
        __syncthreads();
    }

    for (int g = 0; g < 2; g++)
        for (int r = 0; r < 4; r++) {
            const float inv = __builtin_amdgcn_rcpf(o_acc[g][2][r]);
            const int n = n0 + g * 64 + wave * 16 + quad * 4 + r;
            u16* orow = o + ((size_t)b * 1024 + n) * 512 + h * 32;
            orow[l16]      = f2bf(o_acc[g][0][r] * inv);
            orow[16 + l16] = f2bf(o_acc[g][1][r] * inv);
        }
}

extern "C" void kernel_launch(void* const* d_in, const int* in_sizes, int n_in,
                              void* d_out, int out_size, void* d_ws, size_t ws_size,
                              hipStream_t stream) {
    const void* x      = d_in[0];  // (8192,512)
    const void* qkv_w  = d_in[1];  // (1536,512)
    const void* qkv_b  = d_in[2];  // (1536)
    const void* rpb    = d_in[3];  // (16,63,63)
    const void* proj_w = d_in[4];  // (512,512)
    const void* proj_b = d_in[5];  // (512)

    // ws layout (u16 units), ~26.3 MiB. xbf aliases ao (disjoint lifetimes).
    // q lives in d_out (consumed by attn before proj GEMM overwrites d_out).
    u16* ws    = (u16*)d_ws;
    u16* kb    = ws;                   // [b][h][t][c]  8 MiB
    u16* vb    = ws + 4194304;         // [b][h][c][t]  8 MiB
    u16* xbf   = ws + 8388608;         // (8192,512)    8 MiB (== ao)
    u16* ao    = xbf;
    u16* qwbf  = ws + 12582912;        // 1.5 MiB
    u16* pwbf  = ws + 13369344;        // 0.5 MiB
    u16* qbbf  = ws + 13631488;
    u16* pbbf  = ws + 13633024;
    float* rpl2e = (float*)(ws + 13633536);  // 254 KiB
    u16* qb    = (u16*)d_out;          // [b][h][t][c]  8 MiB

    convert_inputs<<<1024, 256, 0, stream>>>(x, qkv_w, qkv_b, proj_w, proj_b, rpb,
                                             xbf, qwbf, qbbf, pwbf, pbbf, rpl2e);

    // QKV GEMM, TRANSPOSED: rows = channels (A = qkv_w), cols = tokens (W-arg = x)
    dim3 g1(8192 / 128, 1536 / 128);
    gemm_bt<1, 128><<<g1, 256, 0, stream>>>(qwbf, xbf, qbbf, nullptr, qb, kb, vb, x, 8192, 512);

    // attention: XCD-swizzled grid (x=h fixes XCD class per (b,h))
    dim3 g2(16, 8, 8);
    attn<<<g2, 256, 0, stream>>>(qb, kb, vb, rpl2e, ao);

    dim3 g3(512 / 128, 8192 / 64);
    gemm_bt<0, 64><<<g3, 256, 0, stream>>>(ao, pwbf, pbbf, d_out, nullptr, nullptr, nullptr, x, 512, 512);
}

// Round 4
// 148.923 us; speedup vs baseline: 1.0976x; 1.0173x over previous
//
#include <hip/hip_runtime.h>

typedef __bf16 bf16x8 __attribute__((ext_vector_type(8)));
typedef float f32x4 __attribute__((ext_vector_type(4)));
typedef unsigned int u32x2 __attribute__((ext_vector_type(2)));
typedef unsigned short u16;
typedef unsigned int u32;

__device__ __forceinline__ float bf2f(u16 v) {
    union { unsigned u; float f; } x; x.u = ((unsigned)v) << 16; return x.f;
}
__device__ __forceinline__ u16 f2bf(float f) {
    union { float f; unsigned u; } x; x.f = f;
    unsigned r = x.u + 0x7fffu + ((x.u >> 16) & 1u);
    return (u16)(r >> 16);
}

// Runtime dtype probe (HW-verified r4): f32 buffer -> low u16 of each word is
// mantissa bits -> bf16-exponent ~uniform (~44% >= 0x90); bf16 buffer -> 0 hits.
__device__ __forceinline__ bool probe_is_f32(const void* xp) {
    const unsigned* p = (const unsigned*)xp;
    int hits = 0;
#pragma unroll
    for (int i = 0; i < 32; i++) {
        const unsigned e = (p[i] >> 7) & 0xffu;
        hits += (e >= 0x90u) ? 1 : 0;
    }
    return hits > 3;
}

__device__ __forceinline__ float ld1(const void* p, size_t i, bool isf32) {
    return isf32 ? ((const float*)p)[i] : bf2f(((const u16*)p)[i]);
}

// Async global->LDS DMA, 16B/lane; LDS dest = wave-uniform base + lane*16.
__device__ __forceinline__ void gl2lds16(const void* g, void* l) {
    __builtin_amdgcn_global_load_lds(
        (const __attribute__((address_space(1))) u32*)g,
        (__attribute__((address_space(3))) u32*)l, 16, 0, 0);
}

// One-shot input normalization: everything -> bf16, rpb -> f32 * log2(e).
__global__ __launch_bounds__(256)
void convert_inputs(const void* __restrict__ x, const void* __restrict__ qw,
                    const void* __restrict__ qb, const void* __restrict__ pw,
                    const void* __restrict__ pb, const void* __restrict__ rp,
                    u16* __restrict__ xbf, u16* __restrict__ qwbf,
                    u16* __restrict__ qbbf, u16* __restrict__ pwbf,
                    u16* __restrict__ pbbf, float* __restrict__ rpl2e)
{
    const bool isf32 = probe_is_f32(x);
    const int gid = blockIdx.x * 256 + threadIdx.x;
    const int gsz = gridDim.x * 256;

    struct Seg { const void* s; u16* d; int n; };
    const Seg segs[5] = {{x, xbf, 4194304}, {qw, qwbf, 786432}, {pw, pwbf, 262144},
                         {qb, qbbf, 1536}, {pb, pbbf, 512}};
    for (int t = 0; t < 5; t++) {
        const int n4 = segs[t].n >> 2;
        if (isf32) {
            const f32x4* s = (const f32x4*)segs[t].s;
            for (int i = gid; i < n4; i += gsz) {
                f32x4 v = s[i];
                ushort4 o;
                o.x = f2bf(v[0]); o.y = f2bf(v[1]); o.z = f2bf(v[2]); o.w = f2bf(v[3]);
                *(ushort4*)(segs[t].d + i * 4) = o;
            }
        } else {
            const ushort4* s = (const ushort4*)segs[t].s;
            for (int i = gid; i < n4; i += gsz) *(ushort4*)(segs[t].d + i * 4) = s[i];
        }
    }
    for (int i = gid; i < 63504; i += gsz)
        rpl2e[i] = ld1(rp, i, isf32) * 1.4426950408889634f;
}

// GEMM D = A(MxK) @ W(NoutxK)^T + bias, pure bf16, fp32 accum. BMx128 tile.
// K-loop unrolled x2 with TWO independent BK=32 LDS buffers per operand:
// one barrier-pair per 64 of K (halves the m97-structure barrier drains)
// while keeping the proven conflict-free stride-32 per-buffer layout.
// MODE 0: bias[col]; dual-dtype row-major store to d_out (probe decides).
// MODE 1 (TRANSPOSED QKV): A = qkv_w (rows = channels), W-arg = x (rows =
//   tokens). D[ch][tok]. bias[row]. which = m0>>9 block-uniform.
//   q,k -> [b][h][t][c] packed ushort4; v -> [b][h][c][t] scalar.
template<int MODE, int BM>
__global__ __launch_bounds__(256, MODE == 1 ? 3 : 4)
void gemm_bt(const u16* __restrict__ A, const u16* __restrict__ W,
             const u16* __restrict__ bias, void* __restrict__ out,
             u16* __restrict__ q_out, u16* __restrict__ k_out, u16* __restrict__ v_out,
             const void* __restrict__ probe, int Nout, int K)
{
    __shared__ __align__(16) u16 As[2][BM * 32];
    __shared__ __align__(16) u16 Ws[2][128 * 32];
    constexpr int RW = BM / 32;            // A-frags per wave

    const int tid  = threadIdx.x;
    const int lane = tid & 63;
    const int wave = tid >> 6;
    const int quad = lane >> 4;
    const int l16  = lane & 15;
    const int m0 = blockIdx.y * BM;
    const int n0 = blockIdx.x * 128;
    const int wm = (wave >> 1) * (BM / 2);
    const int wn = (wave & 1) * 64;

    f32x4 acc[RW][4] = {};

    for (int k0 = 0; k0 < K; k0 += 64) {
        __syncthreads();
        for (int u = 0; u < 2; u++) {
            {
                const u16* g = A + (size_t)(m0 + wave * 16 + (lane >> 2)) * K
                                 + k0 + u * 32 + (lane & 3) * 8;
                u16* l = As[u] + wave * 16 * 32;
                for (int p = 0; p < BM / 64; p++) gl2lds16(g + (size_t)p * 64 * K, l + p * 64 * 32);
            }
            {
                const u16* g = W + (size_t)(n0 + wave * 16 + (lane >> 2)) * K
                                 + k0 + u * 32 + (lane & 3) * 8;
                u16* l = Ws[u] + wave * 16 * 32;
                for (int p = 0; p < 2; p++) gl2lds16(g + (size_t)p * 64 * K, l + p * 64 * 32);
            }
        }
        __syncthreads();

        for (int u = 0; u < 2; u++) {
            bf16x8 af[RW], wf[4];
            for (int i = 0; i < RW; i++)
                af[i] = *(const bf16x8*)(As[u] + (wm + i * 16 + l16) * 32 + quad * 8);
            for (int j = 0; j < 4; j++)
                wf[j] = *(const bf16x8*)(Ws[u] + (wn + j * 16 + l16) * 32 + quad * 8);
            for (int i = 0; i < RW; i++)
                for (int j = 0; j < 4; j++)
                    acc[i][j] = __builtin_amdgcn_mfma_f32_16x16x32_bf16(af[i], wf[j], acc[i][j], 0, 0, 0);
        }
    }

    // D layout per 16x16 tile: row = quad*4 + r, col = l16
    if (MODE == 0) {
        const bool isf32 = probe_is_f32(probe);
        for (int j = 0; j < 4; j++) {
            const int col = n0 + wn + j * 16 + l16;
            const float bv = bf2f(bias[col]);
            for (int i = 0; i < RW; i++) {
                const int rbase = m0 + wm + i * 16 + quad * 4;
                for (int r = 0; r < 4; r++) {
                    const float val = acc[i][j][r] + bv;
                    if (isf32) ((float*)out)[(size_t)(rbase + r) * Nout + col] = val;
                    else       ((u16*)out)[(size_t)(rbase + r) * Nout + col]  = f2bf(val);
                }
            }
        }
    } else {
        const int which = m0 >> 9;       // block-uniform (m0 128-aligned)
        float bv[RW][4];
        for (int i = 0; i < RW; i++) {
            const int row4 = m0 + wm + i * 16 + quad * 4;
            for (int r = 0; r < 4; r++) bv[i][r] = bf2f(bias[row4 + r]);
        }
        for (int j = 0; j < 4; j++) {
            const int tok = n0 + wn + j * 16 + l16;
            const int bi = tok >> 10, t = tok & 1023;
            for (int i = 0; i < RW; i++) {
                const int row4 = m0 + wm + i * 16 + quad * 4;
                const int h = (row4 >> 5) & 15;
                const int c = row4 & 31;
                if (which == 2) {        // v: [b][h][c][t]
                    for (int r = 0; r < 4; r++)
                        v_out[((size_t)(bi * 16 + h) * 32 + c + r) * 1024 + t] =
                            f2bf(acc[i][j][r] + bv[i][r]);
                } else {                 // q,k: [b][h][t][c], 8B packed
                    u16* dst = which ? k_out : q_out;
                    ushort4 pk;
                    pk.x = f2bf(acc[i][j][0] + bv[i][0]);
                    pk.y = f2bf(acc[i][j][1] + bv[i][1]);
                    pk.z = f2bf(acc[i][j][2] + bv[i][2]);
                    pk.w = f2bf(acc[i][j][3] + bv[i][3]);
                    *(ushort4*)(dst + ((size_t)(bi * 16 + h) * 1024 + t) * 32 + c) = pk;
                }
            }
        }
    }
}

// Flash attention, S^T formulation, offset-free softmax, MFMA denominator.
// XCD-SWIZZLED GRID (r10): grid (16,8,8) x=h,y=qt,z=b -> 8 qt-blocks of a
// (b,h) land on one XCD -> K/V served from that XCD's L2. TQ=128/block,
// double-buffered K/V register prefetch, 1 barrier/kt.
//
// r11: K/V direct-from-global REGRESSED (latency-bound at 4 blocks/CU).
// r12: T5 setprio neutral (4-wave lockstep). r13: bias reg-window neutral
// (LDS pipe had slack). Elimination -> attn is LATENCY-bound on the per-kt
// chain QK->softmax->Ps write->Ps read->PV, with grid-limited 4 waves/SIMD.
// r14 (this round): T12 — eliminate the Ps LDS round-trip entirely. The PV
// A-fragment pa[kc] (q-row=l16, k=kc*32+quad*8+i) is a 4-way exchange among
// lanes {l16+16q}: with per-lane words A_j={P[16j+4q],P[16j+4q+1]},
// B_j={+2,+3}:  (u,v)=permlane32_swap(A_2kc,A_2kc+1);
// (w0,w2)=permlane16_swap(u,v); same for B -> (w1,w3);
// pa[kc]={w0,w1,w2,w3}. 8 VALU crossbar ops replace 4 ds_write_b64 +
// 2 ds_read_b128 + exposed LDS latency per g; Ps buffer deleted.
__global__ __launch_bounds__(256, 4)
void attn(const u16* __restrict__ q, const u16* __restrict__ k,
          const u16* __restrict__ vt, const float* __restrict__ rpl2e,
          u16* __restrict__ o)
{
    __shared__ __align__(16) u16 Ks[2][64 * 40];
    __shared__ __align__(16) u16 Vt[2][32 * 72];
    __shared__ float biasT[63 * 37];   // [col][row], 35 rows + 2 pad

    const int tid  = threadIdx.x;
    const int lane = tid & 63;
    const int wave = tid >> 6;
    const int quad = lane >> 4;
    const int l16  = lane & 15;

    const int h  = blockIdx.x;   // 16 heads (fastest -> fixes XCD class)
    const int qt = blockIdx.y;   // 8 q-tiles of 128
    const int b  = blockIdx.z;
    const int n0 = qt * 128;
    const size_t base = ((size_t)(b * 16 + h)) * 32768;  // q,k [t][c]; vt [c][t]

    // ---- prologue: bias region (transposed), kt=0 K/V, Q frags ----
    {
        const int row0 = 28 - 4 * qt;
        for (int idx = tid; idx < 2205; idx += 256) {
            const int rr = idx / 63, cc = idx % 63;
            biasT[cc * 37 + rr] =
                rpl2e[(size_t)h * 3969 + (size_t)(row0 + rr) * 63 + cc];
        }
    }
    uint4 kreg = *(const uint4*)(k + base + (size_t)(tid >> 2) * 32 + (tid & 3) * 8);
    uint4 vreg = *(const uint4*)(vt + base + (size_t)(tid >> 3) * 1024 + (tid & 7) * 8);
    *(uint4*)(Ks[0] + (tid >> 2) * 40 + (tid & 3) * 8) = kreg;
    *(uint4*)(Vt[0] + (tid >> 3) * 72 + (tid & 7) * 8) = vreg;

    bf16x8 qf[2];
    for (int g = 0; g < 2; g++) {
        union { uint4 u; bf16x8 f; } cv;
        cv.u = *(const uint4*)(q + base + (size_t)(n0 + g * 64 + wave * 16 + l16) * 32 + quad * 8);
        qf[g] = cv.f;
    }
    __syncthreads();

    bf16x8 ones;
    for (int i = 0; i < 8; i++) ones[i] = (__bf16)1.0f;

    // o_acc[g][0..1] = O columns ct*16+l16; o_acc[g][2] = denominator l
    f32x4 o_acc[2][3] = {};
    const int bn = (wave & 1) * 16 + l16;   // n & 31 (group-invariant)
    const int w2 = wave >> 1;
    const float SC = 0.25503485724582146f;  // d^-0.5 * log2(e)

    // Bias register window. Rows as function of kt: B = 2*kt - w2 + 1.
    // g=1 uses rows (B, B+1) = X0/X1; g=0 uses rows (B+2, B+3) = Y0/Y1.
    // Per-lane col for slot ci: c = cb + (ci>>2)*16 + (ci&3), kt-invariant.
    const int cb = quad * 4 + 31 - bn;
    float X0[8], X1[8], Y0[8], Y1[8];
#pragma unroll
    for (int ci = 0; ci < 8; ci++) {
        const int c37 = (cb + (ci >> 2) * 16 + (ci & 3)) * 37;
        X0[ci] = biasT[c37 + (1 - w2)];
        X1[ci] = biasT[c37 + (2 - w2)];
        Y0[ci] = biasT[c37 + (3 - w2)];
        Y1[ci] = biasT[c37 + (4 - w2)];
    }

    for (int kt = 0; kt < 16; kt++) {
        const int cur = kt & 1;
        if (kt < 15) {   // prefetch next K/V tile into regs (in flight during compute)
            const int mn = (kt + 1) * 64;
            kreg = *(const uint4*)(k + base + (size_t)(mn + (tid >> 2)) * 32 + (tid & 3) * 8);
            vreg = *(const uint4*)(vt + base + (size_t)(tid >> 3) * 1024 + mn + (tid & 7) * 8);
        }

        bf16x8 kf[4];
#pragma unroll
        for (int j = 0; j < 4; j++)
            kf[j] = *(const bf16x8*)(Ks[cur] + (j * 16 + l16) * 40 + quad * 8);
        bf16x8 vf[2][2];                    // V frags: g-invariant, load once
#pragma unroll
        for (int kc = 0; kc < 2; kc++)
#pragma unroll
            for (int ct = 0; ct < 2; ct++)
                vf[kc][ct] = *(const bf16x8*)(Vt[cur] + (ct * 16 + l16) * 72 + kc * 32 + quad * 8);

#pragma unroll
        for (int g = 0; g < 2; g++) {
            // S^T tile: D col n=l16, row m_loc = j*16 + quad*4 + r
            f32x4 s4[4];
            const f32x4 zero = {};
#pragma unroll
            for (int j = 0; j < 4; j++)
                s4[j] = __builtin_amdgcn_mfma_f32_16x16x32_bf16(kf[j], qf[g], zero, 0, 0, 0);

            // softmax -> per-lane packed bf16 words:
            // Aw[j] = {P[16j+4q+0], P[16j+4q+1]}, Bw[j] = {+2, +3}
            u32 Aw[4], Bw[4];
#pragma unroll
            for (int j = 0; j < 4; j++) {
                u16 pk[4];
#pragma unroll
                for (int r = 0; r < 4; r++) {
                    const int ci = (j & 1) * 4 + r;
                    const float bval = (j >> 1) ? (g ? X1[ci] : Y1[ci])
                                                : (g ? X0[ci] : Y0[ci]);
                    const float pv = __builtin_amdgcn_exp2f(s4[j][r] * SC + bval);
                    union { __bf16 b; u16 u; } cv; cv.b = (__bf16)pv;
                    pk[r] = cv.u;
                }
                Aw[j] = ((u32)pk[1] << 16) | pk[0];
                Bw[j] = ((u32)pk[3] << 16) | pk[2];
            }

            // T12 redistribution: pa[kc] via 2x permlane32_swap + 2x permlane16_swap
#pragma unroll
            for (int kc = 0; kc < 2; kc++) {
                u32x2 ra = __builtin_amdgcn_permlane32_swap(Aw[2 * kc], Aw[2 * kc + 1], false, false);
                u32x2 wa = __builtin_amdgcn_permlane16_swap(ra.x, ra.y, false, false); // w0, w2
                u32x2 rb = __builtin_amdgcn_permlane32_swap(Bw[2 * kc], Bw[2 * kc + 1], false, false);
                u32x2 wb = __builtin_amdgcn_permlane16_swap(rb.x, rb.y, false, false); // w1, w3
                union { u32 w[4]; bf16x8 f; } pa;
                pa.w[0] = wa.x; pa.w[1] = wb.x; pa.w[2] = wa.y; pa.w[3] = wb.y;
#pragma unroll
                for (int ct = 0; ct < 2; ct++)
                    o_acc[g][ct] = __builtin_amdgcn_mfma_f32_16x16x32_bf16(pa.f, vf[kc][ct], o_acc[g][ct], 0, 0, 0);
                o_acc[g][2] = __builtin_amdgcn_mfma_f32_16x16x32_bf16(pa.f, ones, o_acc[g][2], 0, 0, 0);
            }
        }

        if (kt < 15) {
            // rotate bias window: X <- Y, load rows (B+4, B+5) into Y
#pragma unroll
            for (int ci = 0; ci < 8; ci++) { X0[ci] = Y0[ci]; X1[ci] = Y1[ci]; }
            const int nr = 2 * kt - w2 + 5;
#pragma unroll
            for (int ci = 0; ci < 8; ci++) {
                const int c37 = (cb + (ci >> 2) * 16 + (ci & 3)) * 37;
                Y0[ci] = biasT[c37 + nr];
                Y1[ci] = biasT[c37 + nr + 1];
            }
            // write prefetched K/V tile to back buffer
            *(uint4*)(Ks[cur ^ 1] + (tid >> 2) * 40 + (tid & 3) * 8) = kreg;
            *(uint4*)(Vt[cur ^ 1] + (tid >> 3) * 72 + (tid & 7) * 8) = vreg;
        }
        __syncthreads();
    }

    for (int g = 0; g < 2; g++)
        for (int r = 0; r < 4; r++) {
            const float inv = __builtin_amdgcn_rcpf(o_acc[g][2][r]);
            const int n = n0 + g * 64 + wave * 16 + quad * 4 + r;
            u16* orow = o + ((size_t)b * 1024 + n) * 512 + h * 32;
            orow[l16]      = f2bf(o_acc[g][0][r] * inv);
            orow[16 + l16] = f2bf(o_acc[g][1][r] * inv);
        }
}

extern "C" void kernel_launch(void* const* d_in, const int* in_sizes, int n_in,
                              void* d_out, int out_size, void* d_ws, size_t ws_size,
                              hipStream_t stream) {
    const void* x      = d_in[0];  // (8192,512)
    const void* qkv_w  = d_in[1];  // (1536,512)
    const void* qkv_b  = d_in[2];  // (1536)
    const void* rpb    = d_in[3];  // (16,63,63)
    const void* proj_w = d_in[4];  // (512,512)
    const void* proj_b = d_in[5];  // (512)

    // ws layout (u16 units), ~26.3 MiB. xbf aliases ao (disjoint lifetimes).
    // q lives in d_out (consumed by attn before proj GEMM overwrites d_out).
    u16* ws    = (u16*)d_ws;
    u16* kb    = ws;                   // [b][h][t][c]  8 MiB
    u16* vb    = ws + 4194304;         // [b][h][c][t]  8 MiB
    u16* xbf   = ws + 8388608;         // (8192,512)    8 MiB (== ao)
    u16* ao    = xbf;
    u16* qwbf  = ws + 12582912;        // 1.5 MiB
    u16* pwbf  = ws + 13369344;        // 0.5 MiB
    u16* qbbf  = ws + 13631488;
    u16* pbbf  = ws + 13633024;
    float* rpl2e = (float*)(ws + 13633536);  // 254 KiB
    u16* qb    = (u16*)d_out;          // [b][h][t][c]  8 MiB

    convert_inputs<<<1024, 256, 0, stream>>>(x, qkv_w, qkv_b, proj_w, proj_b, rpb,
                                             xbf, qwbf, qbbf, pwbf, pbbf, rpl2e);

    // QKV GEMM, TRANSPOSED: rows = channels (A = qkv_w), cols = tokens (W-arg = x)
    dim3 g1(8192 / 128, 1536 / 128);
    gemm_bt<1, 128><<<g1, 256, 0, stream>>>(qwbf, xbf, qbbf, nullptr, qb, kb, vb, x, 8192, 512);

    // attention: XCD-swizzled grid (x=h fixes XCD class per (b,h))
    dim3 g2(16, 8, 8);
    attn<<<g2, 256, 0, stream>>>(qb, kb, vb, rpl2e, ao);

    dim3 g3(512 / 128, 8192 / 64);
    gemm_bt<0, 64><<<g3, 256, 0, stream>>>(ao, pwbf, pbbf, d_out, nullptr, nullptr, nullptr, x, 512, 512);
}